// Round 1
// baseline (124.549 us; speedup 1.0000x reference)
//
#include <hip/hip_runtime.h>

typedef __bf16  bf16x8 __attribute__((ext_vector_type(8)));
typedef float   f32x4  __attribute__((ext_vector_type(4)));
typedef short   short8 __attribute__((ext_vector_type(8)));

static __device__ __forceinline__ unsigned short f2bf(float f) {
  union { float f; unsigned int u; } v; v.f = f;
  unsigned int u = v.u;
  u += 0x7fffu + ((u >> 16) & 1u);   // round-to-nearest-even
  return (unsigned short)(u >> 16);
}

// e2m1 decode: code = sign<<3 | e<<1 | m ; values {0,.5,1,1.5,2,3,4,6} * sign
static __device__ __forceinline__ float fp4_decode(int qc) {
  int e = (qc >> 1) & 3;
  float m = (float)(qc & 1);
  float mag = (e == 0) ? (0.5f * m)
                       : ((2.0f + m) * 0.5f * (float)(1 << (e - 1)));
  return (qc & 8) ? -mag : mag;
}

// One thread = one 16-element scale block: 64B q in, 4B scale, 32B bf16 out.
__global__ __launch_bounds__(256) void w4a16_dequant_w(
    const int* __restrict__ wq, const float* __restrict__ wsc,
    short* __restrict__ wout, int nblk) {
  int idx = blockIdx.x * 256 + threadIdx.x;
  if (idx >= nblk) return;
  float s = wsc[idx];                       // scales are [O][I/16] flat == block idx
  const int4* qp = (const int4*)wq + (size_t)idx * 4;
  int4 q0 = qp[0], q1 = qp[1], q2 = qp[2], q3 = qp[3];
  short8 r0, r1;
  r0[0] = (short)f2bf(fp4_decode(q0.x) * s);
  r0[1] = (short)f2bf(fp4_decode(q0.y) * s);
  r0[2] = (short)f2bf(fp4_decode(q0.z) * s);
  r0[3] = (short)f2bf(fp4_decode(q0.w) * s);
  r0[4] = (short)f2bf(fp4_decode(q1.x) * s);
  r0[5] = (short)f2bf(fp4_decode(q1.y) * s);
  r0[6] = (short)f2bf(fp4_decode(q1.z) * s);
  r0[7] = (short)f2bf(fp4_decode(q1.w) * s);
  r1[0] = (short)f2bf(fp4_decode(q2.x) * s);
  r1[1] = (short)f2bf(fp4_decode(q2.y) * s);
  r1[2] = (short)f2bf(fp4_decode(q2.z) * s);
  r1[3] = (short)f2bf(fp4_decode(q2.w) * s);
  r1[4] = (short)f2bf(fp4_decode(q3.x) * s);
  r1[5] = (short)f2bf(fp4_decode(q3.y) * s);
  r1[6] = (short)f2bf(fp4_decode(q3.z) * s);
  r1[7] = (short)f2bf(fp4_decode(q3.w) * s);
  short8* op = (short8*)wout + (size_t)idx * 2;
  op[0] = r0;
  op[1] = r1;
}

// x fp32 -> bf16, 8 elements/thread
__global__ __launch_bounds__(256) void w4a16_convert_x(
    const float* __restrict__ x, short* __restrict__ xb, int n8) {
  int idx = blockIdx.x * 256 + threadIdx.x;
  if (idx >= n8) return;
  const float4* xp = (const float4*)x + (size_t)idx * 2;
  float4 a = xp[0], b = xp[1];
  short8 r;
  r[0] = (short)f2bf(a.x); r[1] = (short)f2bf(a.y);
  r[2] = (short)f2bf(a.z); r[3] = (short)f2bf(a.w);
  r[4] = (short)f2bf(b.x); r[5] = (short)f2bf(b.y);
  r[6] = (short)f2bf(b.z); r[7] = (short)f2bf(b.w);
  ((short8*)xb)[idx] = r;
}

// C[M,N] = A[M,K] * B[N,K]^T, bf16 inputs, fp32 out. m97 structure:
// 128x128 tile, BK=64, 4 waves (2x2, each 64x64 = 4x4 frags of 16x16x32).
#define BM 128
#define BN 128
#define BK 64

__global__ __launch_bounds__(256, 2) void w4a16_gemm_bt(
    const short* __restrict__ A, const short* __restrict__ B,
    float* __restrict__ C, int M, int N, int K) {
  __shared__ __attribute__((aligned(16))) short As[BM * BK];   // 16 KB
  __shared__ __attribute__((aligned(16))) short Bs[BN * BK];   // 16 KB

  const int tid  = threadIdx.x;
  const int lane = tid & 63;
  const int wid  = tid >> 6;
  const int wr   = wid >> 1;       // wave row (0..1)
  const int wc   = wid & 1;        // wave col (0..1)

  const int bm = blockIdx.y * BM;
  const int bn = blockIdx.x * BN;

  f32x4 acc[4][4] = {};

  const char* Abase = (const char*)(A + (size_t)bm * K);
  const char* Bbase = (const char*)(B + (size_t)bn * K);
  const size_t rowbytes = (size_t)K * 2;

  // fragment addressing (16x16x32 bf16): lane holds row = lane&15,
  // k = (lane>>4)*8 .. +8 (contiguous) — identical for A and B^T rows.
  const int fr   = lane & 15;
  const int koff = (lane >> 4) * 8;

  for (int kt = 0; kt < K; kt += BK) {
    // ---- stage A,B tiles: 128 rows x 64 bf16 = 16KB each.
    // segment s (0..1023): row = s>>3, 16B-chunk = s&7. LDS dest is linear
    // in s => wave-uniform base + lane*16 (global_load_lds requirement).
#pragma unroll
    for (int i = 0; i < 4; ++i) {
      int s   = i * 256 + tid;
      int row = s >> 3, c16 = s & 7;
      size_t goff = (size_t)row * rowbytes + (size_t)(kt * 2) + c16 * 16;
      __builtin_amdgcn_global_load_lds(
          (const __attribute__((address_space(1))) unsigned int*)(Abase + goff),
          (__attribute__((address_space(3))) unsigned int*)(As + s * 8), 16, 0, 0);
      __builtin_amdgcn_global_load_lds(
          (const __attribute__((address_space(1))) unsigned int*)(Bbase + goff),
          (__attribute__((address_space(3))) unsigned int*)(Bs + s * 8), 16, 0, 0);
    }
    __syncthreads();

#pragma unroll
    for (int kk = 0; kk < 2; ++kk) {
      bf16x8 af[4], bf[4];
#pragma unroll
      for (int mi = 0; mi < 4; ++mi)
        af[mi] = *(const bf16x8*)(As + (wr * 64 + mi * 16 + fr) * BK + kk * 32 + koff);
#pragma unroll
      for (int ni = 0; ni < 4; ++ni)
        bf[ni] = *(const bf16x8*)(Bs + (wc * 64 + ni * 16 + fr) * BK + kk * 32 + koff);
#pragma unroll
      for (int mi = 0; mi < 4; ++mi)
#pragma unroll
        for (int ni = 0; ni < 4; ++ni)
          acc[mi][ni] = __builtin_amdgcn_mfma_f32_16x16x32_bf16(
              af[mi], bf[ni], acc[mi][ni], 0, 0, 0);
    }
    __syncthreads();
  }

  // ---- epilogue: C/D map (m89/m91): col = lane&15, row = (lane>>4)*4 + reg
  const int cn = lane & 15;
  const int rb = (lane >> 4) * 4;
#pragma unroll
  for (int mi = 0; mi < 4; ++mi)
#pragma unroll
    for (int ni = 0; ni < 4; ++ni) {
      int m0 = bm + wr * 64 + mi * 16 + rb;
      int n0 = bn + wc * 64 + ni * 16 + cn;
#pragma unroll
      for (int r = 0; r < 4; ++r)
        C[(size_t)(m0 + r) * N + n0] = acc[mi][ni][r];
    }
}

extern "C" void kernel_launch(void* const* d_in, const int* in_sizes, int n_in,
                              void* d_out, int out_size, void* d_ws, size_t ws_size,
                              hipStream_t stream) {
  const float* x   = (const float*)d_in[0];
  const float* wsc = (const float*)d_in[1];
  const int*   wq  = (const int*)d_in[2];
  float* out = (float*)d_out;

  const int K = 4096;                 // in_features
  const int N = in_sizes[2] / K;      // out_features = 4096
  const int M = in_sizes[0] / K;      // batch*seq = 2048

  // workspace layout: W bf16 [N*K] then X bf16 [M*K]
  short* Wb = (short*)d_ws;
  short* Xb = Wb + (size_t)N * K;

  int nblk = (N * K) / 16;
  w4a16_dequant_w<<<nblk / 256, 256, 0, stream>>>(wq, wsc, Wb, nblk);
  int n8 = (M * K) / 8;
  w4a16_convert_x<<<n8 / 256, 256, 0, stream>>>(x, Xb, n8);

  dim3 grid(N / BN, M / BM);
  w4a16_gemm_bt<<<grid, 256, 0, stream>>>(Xb, Wb, out, M, N, K);
}